// Round 8
// baseline (534.631 us; speedup 1.0000x reference)
//
#include <hip/hip_runtime.h>
#include <cstdint>
#include <cstddef>

typedef __bf16 bf16;
typedef __bf16 bf16x8 __attribute__((ext_vector_type(8)));
typedef float  f32x4  __attribute__((ext_vector_type(4)));
typedef unsigned short u16;

#define MD ((size_t)8388608)   // 16384*512 elements

// ---- async global->LDS 16B copy. LDS dest = wave-uniform base + lane*16 ----
__device__ __forceinline__ void async_copy16(const bf16* gp, bf16* lp) {
  __builtin_amdgcn_global_load_lds(
      (__attribute__((address_space(1))) void*)(gp),
      (__attribute__((address_space(3))) void*)(lp), 16, 0, 0);
}

// ---- inline dtype probe: wave ballots the 64 even (low-half) u16s of X. ----
__device__ __forceinline__ int is_f32(const u16* __restrict__ x) {
  const int e = (x[(threadIdx.x & 63) * 2] >> 7) & 0xFF;
  return __ballot(e >= 141) != 0ull;
}

// =====================================================================
// Batched conversion of all 20 float tensors into bf16 staging in ws.
// =====================================================================
struct ConvSrc { const void* p[20]; };

__global__ __launch_bounds__(256)
void convert_all(ConvSrc s, bf16* __restrict__ ws, const u16* __restrict__ xprobe)
{
  const int n[20] = {8388608, 8388608,
                     262144, 262144, 262144, 262144, 262144, 262144, 262144, 262144,
                     1048576, 2048, 1048576, 512, 512, 512, 512, 512, 512, 512};
  const unsigned int doff[20] = {
      41943040u, 50331648u,
      58720256u, 58982400u, 59244544u, 59506688u,
      59768832u, 60030976u, 60293120u, 60555264u,
      60817408u, 61865984u, 61868032u, 62916608u,
      62917120u, 62917632u, 62918144u, 62918656u, 62919168u, 62919680u};

  const int f32 = is_f32(xprobe);

  int bi = blockIdx.x;
  int idx = 0, b0 = 0;
  for (; idx < 20; ++idx) {
    const int nb = (n[idx] + 2047) >> 11;
    if (bi < b0 + nb) break;
    b0 += nb;
  }
  const int i = ((bi - b0) << 11) + threadIdx.x * 8;
  if (i >= n[idx]) return;
  bf16* dst = ws + doff[idx] + i;
  if (f32) {
    const float* sp = (const float*)s.p[idx] + i;
    f32x4 a = *(const f32x4*)sp;
    f32x4 b = *(const f32x4*)(sp + 4);
    bf16x8 o;
#pragma unroll
    for (int e = 0; e < 4; ++e) { o[e] = (bf16)a[e]; o[4 + e] = (bf16)b[e]; }
    *(bf16x8*)dst = o;
  } else {
    *(bf16x8*)dst = *(const bf16x8*)((const bf16*)s.p[idx] + i);
  }
}

// =====================================================================
// gemm4p body (round-2 verified schedule, BM=256/128), device function
// so one kernel can run two independent GEMM jobs (tail-filling merge).
// Counted vmcnt (6 for BM=256, 4 for BM=128), never 0 in loop.
// XCD remap per job: requires nblk % 8 == 0 (all grids qualify).
// =====================================================================
template<int MODE, int BM>
__device__ __forceinline__ void gemm4p_body(
    const bf16* __restrict__ A, const bf16* __restrict__ B,
    const bf16* __restrict__ bias, bf16* __restrict__ C,
    int N, int K, int gx, int bid, int nblk, bf16* AsP, bf16* BsP)
{
  constexpr int BN = 256, T = 512, WM = 2, WN = 4;
  constexpr int WR = BM / WM;          // rows per wave (128 or 64)
  constexpr int MI = WR / 16;          // M-frags per wave (8 or 4)
  constexpr int NJ = 4;                // 64 cols per wave
  constexpr int MH = MI / 2;           // frags per mh phase (4 or 2)
  constexpr int LA = BM * 8 / T;       // A loads/thread per tile (4 or 2)
  constexpr int LB = 4;
  static_assert(LA == 4 || LA == 2, "schedule assumes BM in {256,128}");

  const int t    = threadIdx.x;
  const int lane = t & 63;
  const int quad = lane >> 4;
  const int l15  = lane & 15;
  const int wave = t >> 6;
  const int wm   = wave >> 2;
  const int wn   = wave & 3;

  const int chunk = nblk >> 3;
  const int lin   = (bid & 7) * chunk + (bid >> 3);
  const int m0    = (lin / gx) * BM;
  const int n0    = (lin % gx) * BN;

  const bf16* Ag = A + (size_t)m0 * K;
  const bf16* Bg = B + (size_t)n0 * K;
  const int wbase = wave << 6;

  auto stA = [&](int kt, int r, int buf) {
    const int s   = r * T + t;
    const int row = s >> 3;
    const int cg  = s & 7;
    async_copy16(Ag + (size_t)row * K + (kt << 6) + ((cg ^ (row & 7)) << 3),
                 AsP + buf * (BM * 64) + ((size_t)(r * T + wbase) << 3));
  };
  auto stB = [&](int kt, int r, int buf) {
    const int s   = r * T + t;
    const int row = s >> 3;
    const int cg  = s & 7;
    async_copy16(Bg + (size_t)row * K + (kt << 6) + ((cg ^ (row & 7)) << 3),
                 BsP + buf * (BN * 64) + ((size_t)(r * T + wbase) << 3));
  };
  auto ldfrag = [&](const bf16* base, int row, int ks) -> bf16x8 {
    return *(const bf16x8*)(base + row * 64 + ((((ks << 2) + quad) ^ (row & 7)) << 3));
  };

  const f32x4 fz = {0.f, 0.f, 0.f, 0.f};
  f32x4 acc[MI][NJ];
#pragma unroll
  for (int i = 0; i < MI; ++i)
#pragma unroll
    for (int j = 0; j < NJ; ++j) acc[i][j] = fz;

  const int nkt = K >> 6;

  // ---- prologue ----
#pragma unroll
  for (int r = 0; r < LA; ++r) stA(0, r, 0);
#pragma unroll
  for (int r = 0; r < LB; ++r) stB(0, r, 0);
  if constexpr (LA == 4) { stA(1, 0, 1); stA(1, 2, 1); }
#pragma unroll
  for (int r = 0; r < LB; ++r) stB(1, r, 1);
  if constexpr (LA == 4) asm volatile("s_waitcnt vmcnt(6)" ::: "memory");
  else                   asm volatile("s_waitcnt vmcnt(4)" ::: "memory");
  __builtin_amdgcn_s_barrier();

  for (int j = 0; j < nkt; ++j) {
    const int cb = j & 1;
    const bf16* a_l = AsP + cb * (BM * 64);
    const bf16* b_l = BsP + cb * (BN * 64);
    const int kN = (j + 1 < nkt) ? j + 1 : nkt - 1;
    const int kF = (j + 2 < nkt) ? j + 2 : nkt - 1;

    bf16x8 bfv[NJ];
    bf16x8 af[MH];

    // ---------------- p0: (mh0, ks0) ----------------
#pragma unroll
    for (int nj = 0; nj < NJ; ++nj) bfv[nj] = ldfrag(b_l, wn * 64 + nj * 16 + l15, 0);
#pragma unroll
    for (int mi = 0; mi < MH; ++mi) af[mi] = ldfrag(a_l, wm * WR + mi * 16 + l15, 0);
    if constexpr (LA == 4) { stA(kN, 1, cb ^ 1); stA(kN, 3, cb ^ 1); }
    else                   { stA(kN, 0, cb ^ 1); stA(kN, 1, cb ^ 1); }
    __builtin_amdgcn_s_barrier();
    asm volatile("s_waitcnt lgkmcnt(0)" ::: "memory");
    __builtin_amdgcn_sched_barrier(0);
    __builtin_amdgcn_s_setprio(1);
#pragma unroll
    for (int mi = 0; mi < MH; ++mi)
#pragma unroll
      for (int nj = 0; nj < NJ; ++nj)
        acc[mi][nj] = __builtin_amdgcn_mfma_f32_16x16x32_bf16(af[mi], bfv[nj],
                                                              acc[mi][nj], 0, 0, 0);
    __builtin_amdgcn_s_setprio(0);
    __builtin_amdgcn_s_barrier();

    // ---------------- p1: (mh1, ks0) ----------------
#pragma unroll
    for (int mi = 0; mi < MH; ++mi) af[mi] = ldfrag(a_l, wm * WR + (MH + mi) * 16 + l15, 0);
    __builtin_amdgcn_s_barrier();
    asm volatile("s_waitcnt lgkmcnt(0)" ::: "memory");
    __builtin_amdgcn_sched_barrier(0);
    __builtin_amdgcn_s_setprio(1);
#pragma unroll
    for (int mi = 0; mi < MH; ++mi)
#pragma unroll
      for (int nj = 0; nj < NJ; ++nj)
        acc[MH + mi][nj] = __builtin_amdgcn_mfma_f32_16x16x32_bf16(af[mi], bfv[nj],
                                                                   acc[MH + mi][nj], 0, 0, 0);
    __builtin_amdgcn_s_setprio(0);
    __builtin_amdgcn_s_barrier();

    // ---------------- p2: (mh0, ks1) ----------------
#pragma unroll
    for (int nj = 0; nj < NJ; ++nj) bfv[nj] = ldfrag(b_l, wn * 64 + nj * 16 + l15, 1);
#pragma unroll
    for (int mi = 0; mi < MH; ++mi) af[mi] = ldfrag(a_l, wm * WR + mi * 16 + l15, 1);
    __builtin_amdgcn_s_barrier();
    asm volatile("s_waitcnt lgkmcnt(0)" ::: "memory");
    __builtin_amdgcn_sched_barrier(0);
    __builtin_amdgcn_s_setprio(1);
#pragma unroll
    for (int mi = 0; mi < MH; ++mi)
#pragma unroll
      for (int nj = 0; nj < NJ; ++nj)
        acc[mi][nj] = __builtin_amdgcn_mfma_f32_16x16x32_bf16(af[mi], bfv[nj],
                                                              acc[mi][nj], 0, 0, 0);
    __builtin_amdgcn_s_setprio(0);
    __builtin_amdgcn_s_barrier();

    // ---------------- p3: (mh1, ks1) ----------------
#pragma unroll
    for (int mi = 0; mi < MH; ++mi) af[mi] = ldfrag(a_l, wm * WR + (MH + mi) * 16 + l15, 1);
    if constexpr (LA == 4) { stA(kF, 0, cb); stA(kF, 2, cb); }
#pragma unroll
    for (int r = 0; r < LB; ++r) stB(kF, r, cb);
    __builtin_amdgcn_s_barrier();
    asm volatile("s_waitcnt lgkmcnt(0)" ::: "memory");
    __builtin_amdgcn_sched_barrier(0);
    __builtin_amdgcn_s_setprio(1);
#pragma unroll
    for (int mi = 0; mi < MH; ++mi)
#pragma unroll
      for (int nj = 0; nj < NJ; ++nj)
        acc[MH + mi][nj] = __builtin_amdgcn_mfma_f32_16x16x32_bf16(af[mi], bfv[nj],
                                                                   acc[MH + mi][nj], 0, 0, 0);
    __builtin_amdgcn_s_setprio(0);
    if constexpr (LA == 4) asm volatile("s_waitcnt vmcnt(6)" ::: "memory");
    else                   asm volatile("s_waitcnt vmcnt(4)" ::: "memory");
    __builtin_amdgcn_s_barrier();
  }

  asm volatile("s_waitcnt vmcnt(0)" ::: "memory");    // drain LDS-DMA

  // ---- epilogue ----
#pragma unroll
  for (int mi = 0; mi < MI; ++mi) {
    const int m = m0 + wm * WR + mi * 16 + quad * 4;
#pragma unroll
    for (int nj = 0; nj < NJ; ++nj) {
      const int n = n0 + wn * 64 + nj * 16 + l15;
      float bv = 0.f;
      if (MODE >= 1) bv = (float)bias[n];
#pragma unroll
      for (int r = 0; r < 4; ++r) {
        float v = acc[mi][nj][r];
        if (MODE >= 1) v += bv;
        if (MODE == 1) v = v > 0.f ? v : 0.01f * v;
        C[(size_t)(m + r) * N + n] = (bf16)v;
      }
    }
  }
}

template<int MODE, int BM>
__global__ __launch_bounds__(512, 1)
void gemm4p(const bf16* __restrict__ A, const bf16* __restrict__ B,
            const bf16* __restrict__ bias, bf16* __restrict__ C,
            int N, int K, int gx)
{
  __shared__ __attribute__((aligned(16))) bf16 As[2 * BM * 64];
  __shared__ __attribute__((aligned(16))) bf16 Bs[2 * 256 * 64];
  gemm4p_body<MODE, BM>(A, B, bias, C, N, K, gx, blockIdx.x, gridDim.x, As, Bs);
}

// Merged QKV (384 blocks) + KV2 (256 blocks); outputs must be disjoint
// (QKV spans 3*MD from C0, KV2 spans 2*MD from C1).
__global__ __launch_bounds__(512, 1)
void gemm4p_dual(const bf16* __restrict__ A0, const bf16* __restrict__ B0,
                 bf16* __restrict__ C0,
                 const bf16* __restrict__ A1, const bf16* __restrict__ B1,
                 bf16* __restrict__ C1)
{
  __shared__ __attribute__((aligned(16))) bf16 As[2 * 256 * 64];
  __shared__ __attribute__((aligned(16))) bf16 Bs[2 * 256 * 64];
  const int bid = blockIdx.x;
  if (bid < 384)
    gemm4p_body<0, 256>(A0, B0, nullptr, C0, 1536, 512, 6, bid, 384, As, Bs);
  else
    gemm4p_body<0, 256>(A1, B1, nullptr, C1, 1024, 512, 4, bid - 384, 256, As, Bs);
}

// =====================================================================
// Flash attention v4: round-6 algorithm (static softmax, verified absmax
// 0.031) with XOR-SWIZZLED LDS. Old [.][72] layout had bank-start
// 4*((l15+quad)&7) on every b128 fragment read -> 8-way conflict (2.94x,
// m136). New: stride-64, element (row,col) at row*64 +
// ((col8 ^ (row&7))<<3) + (col&7) — the gemm-verified 0-conflict pattern.
// Writer and reader use the identical mapping (bijective per row);
// vector-8 accesses preserved (XOR permutes whole 8-elem blocks).
// =====================================================================
__global__ __launch_bounds__(256, 4)
void flash_attn(const bf16* __restrict__ Qp, const bf16* __restrict__ Kp,
                const bf16* __restrict__ Vp, bf16* __restrict__ Op,
                const int* __restrict__ vlen, int per_query, int sq, int skv)
{
  __shared__ __attribute__((aligned(16))) bf16 Ks[64 * 64];
  __shared__ __attribute__((aligned(16))) bf16 VsT[64 * 64];   // [d][k] logical
  __shared__ __attribute__((aligned(16))) bf16 Ps[4][32 * 64]; // per-wave [q][k]
  __shared__ int vlmax_sh;

  const int t    = threadIdx.x;
  const int wave = t >> 6;
  const int lane = t & 63;
  const int quad = lane >> 4;
  const int l15  = lane & 15;
  const int rx   = l15 & 7;          // row&7 for rows of form nt*16+l15
  const int bx   = blockIdx.x;
  const int qt   = bx >> 8;          // 0..3 (slowest)
  const int h    = bx & 7;
  const int b    = (bx >> 3) & 31;
  const int q0   = qt * 128 + wave * 32;

  bf16x8 qfrag[2][2];
#pragma unroll
  for (int mt = 0; mt < 2; ++mt)
#pragma unroll
    for (int ks = 0; ks < 2; ++ks)
      qfrag[mt][ks] = *(const bf16x8*)(Qp +
          (size_t)(b * 512 + q0 + mt * 16 + l15) * sq + h * 64 + ks * 32 + quad * 8);

  int vl_r[2][4];
  int myvl = 1;
#pragma unroll
  for (int mt = 0; mt < 2; ++mt)
#pragma unroll
    for (int r = 0; r < 4; ++r) {
      const int q = q0 + mt * 16 + quad * 4 + r;
      const int v = per_query ? vlen[b * 512 + q] : vlen[b];
      vl_r[mt][r] = v;
      myvl = v > myvl ? v : myvl;
    }

  if (t == 0) vlmax_sh = 1;
  __syncthreads();
#pragma unroll
  for (int off = 1; off < 64; off <<= 1) {
    const int o = __shfl_xor(myvl, off);
    myvl = o > myvl ? o : myvl;
  }
  if (lane == 0) atomicMax(&vlmax_sh, myvl);
  __syncthreads();
  const int ktiles = (vlmax_sh + 63) >> 6;

  const f32x4 fz = {0.f, 0.f, 0.f, 0.f};
  float l_part[2][4] = {{0.f,0.f,0.f,0.f},{0.f,0.f,0.f,0.f}};
  f32x4 o_acc[2][4];
#pragma unroll
  for (int mt = 0; mt < 2; ++mt)
#pragma unroll
    for (int nt = 0; nt < 4; ++nt) o_acc[mt][nt] = fz;

  for (int kt = 0; kt < ktiles; ++kt) {
    const int k0 = kt * 64;
    __syncthreads();   // prior K/V tiles fully consumed
    {
      // K stage: coalesced global, swizzled LDS placement
      const int r0 = t >> 3;          // 0..31
      const int c8 = t & 7;           // col-block
      const int p8 = (c8 ^ (r0 & 7)) << 3;
      const bf16* g = Kp + (size_t)(b * 512 + k0 + r0) * skv + h * 64 + c8 * 8;
      *(bf16x8*)&Ks[r0 * 64 + p8]        = *(const bf16x8*)g;
      *(bf16x8*)&Ks[(r0 + 32) * 64 + p8] = *(const bf16x8*)(g + (size_t)32 * skv);
    }
    {
      // V transpose stage: row = d (lane), col-blocks wave*2, wave*2+1 (k)
      const bf16* g = Vp + (size_t)(b * 512 + k0 + wave * 16) * skv + h * 64 + lane;
      bf16x8 lo, hi;
#pragma unroll
      for (int kk = 0; kk < 8; ++kk) lo[kk] = g[(size_t)kk * skv];
#pragma unroll
      for (int kk = 0; kk < 8; ++kk) hi[kk] = g[(size_t)(kk + 8) * skv];
      const int la7 = lane & 7;
      *(bf16x8*)&VsT[lane * 64 + (((wave * 2)     ^ la7) << 3)] = lo;
      *(bf16x8*)&VsT[lane * 64 + (((wave * 2 + 1) ^ la7) << 3)] = hi;
    }
    __syncthreads();

    // ---- QK^T ----
    f32x4 s[2][4];
#pragma unroll
    for (int mt = 0; mt < 2; ++mt)
#pragma unroll
      for (int nt = 0; nt < 4; ++nt) s[mt][nt] = fz;
#pragma unroll
    for (int ks = 0; ks < 2; ++ks)
#pragma unroll
      for (int nt = 0; nt < 4; ++nt) {
        const int krow = nt * 16 + l15;
        const bf16x8 bk = *(const bf16x8*)&Ks[krow * 64 + ((((ks << 2) + quad) ^ rx) << 3)];
        s[0][nt] = __builtin_amdgcn_mfma_f32_16x16x32_bf16(qfrag[0][ks], bk, s[0][nt], 0, 0, 0);
        s[1][nt] = __builtin_amdgcn_mfma_f32_16x16x32_bf16(qfrag[1][ks], bk, s[1][nt], 0, 0, 0);
      }

    // ---- static softmax: p = masked ? 0 : exp(s/8); accumulate l ----
#pragma unroll
    for (int mt = 0; mt < 2; ++mt)
#pragma unroll
      for (int nt = 0; nt < 4; ++nt) {
        const int k_abs = k0 + nt * 16 + l15;
        const int kcol  = nt * 16 + l15;
#pragma unroll
        for (int r = 0; r < 4; ++r) {
          const float p = (k_abs < vl_r[mt][r]) ? __expf(s[mt][nt][r] * 0.125f) : 0.f;
          l_part[mt][r] += p;
          const int q = mt * 16 + quad * 4 + r;
          Ps[wave][q * 64 + ((((kcol >> 3) ^ (q & 7)) << 3) | (kcol & 7))] = (bf16)p;
        }
      }

    // ---- O += P @ V (Ps per-wave; same-wave DS ordering suffices) ----
#pragma unroll
    for (int ks = 0; ks < 2; ++ks) {
      const int cb = (ks << 2) + quad;
      const bf16x8 ap0 = *(const bf16x8*)&Ps[wave][l15 * 64        + ((cb ^ rx) << 3)];
      const bf16x8 ap1 = *(const bf16x8*)&Ps[wave][(16 + l15) * 64 + ((cb ^ rx) << 3)];
#pragma unroll
      for (int nt = 0; nt < 4; ++nt) {
        const int vrow = nt * 16 + l15;
        const bf16x8 bv = *(const bf16x8*)&VsT[vrow * 64 + ((cb ^ rx) << 3)];
        o_acc[0][nt] = __builtin_amdgcn_mfma_f32_16x16x32_bf16(ap0, bv, o_acc[0][nt], 0, 0, 0);
        o_acc[1][nt] = __builtin_amdgcn_mfma_f32_16x16x32_bf16(ap1, bv, o_acc[1][nt], 0, 0, 0);
      }
    }
  }

  // ---- epilogue ----
#pragma unroll
  for (int mt = 0; mt < 2; ++mt)
#pragma unroll
    for (int r = 0; r < 4; ++r) {
      float l = l_part[mt][r];
#pragma unroll
      for (int off = 1; off < 16; off <<= 1)
        l += __shfl_xor(l, off);
      const float inv_l = (l > 0.f) ? (1.f / l) : 0.f;
      const int q = q0 + mt * 16 + quad * 4 + r;
#pragma unroll
      for (int nt = 0; nt < 4; ++nt)
        Op[(size_t)(b * 512 + q) * 512 + h * 64 + nt * 16 + l15] =
            (bf16)(o_acc[mt][nt][r] * inv_l);
    }
}

// =====================================================================
// AddNorm (internal, bf16 out). One wave per 512-row.
// =====================================================================
__global__ __launch_bounds__(256)
void add_layernorm(const bf16* X, const bf16* R,
                   const bf16* __restrict__ gamma, const bf16* __restrict__ beta,
                   bf16* Out)
{
  const int t    = threadIdx.x;
  const int wave = t >> 6;
  const int lane = t & 63;
  const size_t row  = (size_t)blockIdx.x * 4 + wave;
  const size_t base = row * 512 + lane * 8;

  bf16x8 xv = *(const bf16x8*)(X + base);
  bf16x8 rv = *(const bf16x8*)(R + base);
  float v[8];
  float sum = 0.f, ss = 0.f;
#pragma unroll
  for (int i = 0; i < 8; ++i) {
    v[i] = (float)xv[i] + (float)rv[i];
    sum += v[i];
    ss  += v[i] * v[i];
  }
#pragma unroll
  for (int off = 1; off < 64; off <<= 1) {
    sum += __shfl_xor(sum, off);
    ss  += __shfl_xor(ss, off);
  }
  const float mean = sum * (1.f / 512.f);
  const float var  = ss * (1.f / 512.f) - mean * mean;
  const float rstd = rsqrtf(var + 1e-5f);

  bf16x8 gv = *(const bf16x8*)(gamma + lane * 8);
  bf16x8 bv = *(const bf16x8*)(beta + lane * 8);
  bf16x8 ov;
#pragma unroll
  for (int i = 0; i < 8; ++i)
    ov[i] = (bf16)(((v[i] - mean) * rstd) * (float)gv[i] + (float)bv[i]);
  *(bf16x8*)(Out + base) = ov;
}

// =====================================================================
// Final AddNorm: writes d_out as fp32 or bf16 per the inline dtype probe.
// =====================================================================
__global__ __launch_bounds__(256)
void add_layernorm_out(const bf16* X, const bf16* R,
                       const bf16* __restrict__ gamma, const bf16* __restrict__ beta,
                       void* Out, const u16* __restrict__ xprobe)
{
  const int t    = threadIdx.x;
  const int wave = t >> 6;
  const int lane = t & 63;
  const size_t row  = (size_t)blockIdx.x * 4 + wave;
  const size_t base = row * 512 + lane * 8;

  const int f32 = is_f32(xprobe);

  bf16x8 xv = *(const bf16x8*)(X + base);
  bf16x8 rv = *(const bf16x8*)(R + base);
  float v[8];
  float sum = 0.f, ss = 0.f;
#pragma unroll
  for (int i = 0; i < 8; ++i) {
    v[i] = (float)xv[i] + (float)rv[i];
    sum += v[i];
    ss  += v[i] * v[i];
  }
#pragma unroll
  for (int off = 1; off < 64; off <<= 1) {
    sum += __shfl_xor(sum, off);
    ss  += __shfl_xor(ss, off);
  }
  const float mean = sum * (1.f / 512.f);
  const float var  = ss * (1.f / 512.f) - mean * mean;
  const float rstd = rsqrtf(var + 1e-5f);

  bf16x8 gv = *(const bf16x8*)(gamma + lane * 8);
  bf16x8 bv = *(const bf16x8*)(beta + lane * 8);
  float o[8];
#pragma unroll
  for (int i = 0; i < 8; ++i)
    o[i] = ((v[i] - mean) * rstd) * (float)gv[i] + (float)bv[i];

  if (f32) {
    float* op = (float*)Out + base;
    f32x4 o0 = {o[0], o[1], o[2], o[3]};
    f32x4 o1 = {o[4], o[5], o[6], o[7]};
    *(f32x4*)op       = o0;
    *(f32x4*)(op + 4) = o1;
  } else {
    bf16x8 ov;
#pragma unroll
    for (int i = 0; i < 8; ++i) ov[i] = (bf16)o[i];
    *(bf16x8*)((bf16*)Out + base) = ov;
  }
}

// =====================================================================
// Lifetime map (round-6 verified):
//   dual : reads Xb(S5),Eb(S6),W   writes QKV->S0..S2, KV2->S3..S4
//   attn1: reads S0-span(QKV)      writes O1 -> Eb      [Eb dead]
//   Wo1  : reads S6(Eb)            writes X2 -> S0      [QKV dead]
//   LN1  : reads Xb,S0             writes Y  -> S1
//   Wq2  : reads S1                writes Q2 -> S2
//   attn2: reads S2, S3..S4(KV2)   writes O2 -> S0
//   Wo2  : reads S0                writes Y2 -> S2
//   LN2  : reads S1,S2             writes Z  -> S4      [KV2 dead]
//   FFN1 : reads S4                writes H  -> S0..S3
//   FFN2 : reads S0..S3            writes F  -> Xb      [Xb dead]
//   LN3  : reads S4,Xb             writes d_out
// =====================================================================
extern "C" void kernel_launch(void* const* d_in, const int* in_sizes, int n_in,
                              void* d_out, int out_size, void* d_ws, size_t ws_size,
                              hipStream_t stream)
{
  (void)in_sizes; (void)n_in; (void)out_size; (void)ws_size;

  const int* dvl = (const int*)d_in[2];
  const int* evl = (const int*)d_in[3];
  const u16* xprobe = (const u16*)d_in[0];

  bf16* ws = (bf16*)d_ws;
  bf16* S0 = ws;
  bf16* S1 = ws + 1 * MD;
  bf16* S2 = ws + 2 * MD;
  bf16* S3 = ws + 3 * MD;
  bf16* S4 = ws + 4 * MD;
  bf16* Xb = ws + 5 * MD;
  bf16* Eb = ws + 6 * MD;
  bf16* W  = ws + 7 * MD;
  const bf16 *Wq1 = W,
             *Wo1 = W + 786432,   *Wq2 = W + 1048576, *Wk2 = W + 1310720,
             *Wo2 = W + 1835008,
             *W1  = W + 2097152,  *b1  = W + 3145728,
             *W2  = W + 3147776,  *b2  = W + 4196352,
             *g1  = W + 4196864,  *be1 = W + 4197376,
             *g2  = W + 4197888,  *be2 = W + 4198400,
             *g3  = W + 4198912,  *be3 = W + 4199424;

  // ---- ingest (dtype probe inlined per wave) ----
  ConvSrc cs;
  cs.p[0] = d_in[0];  cs.p[1] = d_in[1];
  for (int k = 0; k < 12; ++k) cs.p[2 + k] = d_in[4 + k];
  for (int k = 0; k < 6; ++k)  cs.p[14 + k] = d_in[16 + k];
  convert_all<<<dim3(10248), dim3(256), 0, stream>>>(cs, ws, xprobe);

  dim3 blk256(256);
  dim3 blk512(512);

  // ---- QKV + KV2 merged: disjoint outputs S0..S2 / S3..S4 ----
  gemm4p_dual<<<dim3(640), blk512, 0, stream>>>(Xb, Wq1, S0, Eb, Wk2, S3);

  // ---- self-attention ----
  flash_attn<<<dim3(1024), blk256, 0, stream>>>(S0, S0 + 512, S0 + 1024, Eb, dvl, 1, 1536, 1536);
  gemm4p<0,128><<<dim3(256), blk512, 0, stream>>>(Eb, Wo1, nullptr, S0, 512, 512, 2);
  add_layernorm<<<dim3(4096), blk256, 0, stream>>>(Xb, S0, g1, be1, S1);   // Y

  // ---- cross-attention (KV2 in S3..S4) ----
  gemm4p<0,128><<<dim3(256), blk512, 0, stream>>>(S1, Wq2, nullptr, S2, 512, 512, 2);
  flash_attn<<<dim3(1024), blk256, 0, stream>>>(S2, S3, S3 + 512, S0, evl, 0, 512, 1024);
  gemm4p<0,128><<<dim3(256), blk512, 0, stream>>>(S0, Wo2, nullptr, S2, 512, 512, 2);
  add_layernorm<<<dim3(4096), blk256, 0, stream>>>(S1, S2, g2, be2, S4);   // Z

  // ---- FFN ----
  gemm4p<1,256><<<dim3(512), blk512, 0, stream>>>(S4, W1, b1, S0, 2048, 512, 8);
  gemm4p<2,128><<<dim3(256), blk512, 0, stream>>>(S0, W2, b2, Xb, 512, 2048, 2);
  add_layernorm_out<<<dim3(4096), blk256, 0, stream>>>(S4, Xb, g3, be3, d_out, xprobe);
}

// Round 10
// 461.684 us; speedup vs baseline: 1.1580x; 1.1580x over previous
//
#include <hip/hip_runtime.h>
#include <cstdint>
#include <cstddef>

typedef __bf16 bf16;
typedef __bf16 bf16x8 __attribute__((ext_vector_type(8)));
typedef float  f32x4  __attribute__((ext_vector_type(4)));
typedef unsigned short u16;

#define MD ((size_t)8388608)   // 16384*512 elements

// ---- async global->LDS 16B copy. LDS dest = wave-uniform base + lane*16 ----
__device__ __forceinline__ void async_copy16(const bf16* gp, bf16* lp) {
  __builtin_amdgcn_global_load_lds(
      (__attribute__((address_space(1))) void*)(gp),
      (__attribute__((address_space(3))) void*)(lp), 16, 0, 0);
}

// ---- inline dtype probe: wave ballots the 64 even (low-half) u16s of X. ----
__device__ __forceinline__ int is_f32(const u16* __restrict__ x) {
  const int e = (x[(threadIdx.x & 63) * 2] >> 7) & 0xFF;
  return __ballot(e >= 141) != 0ull;
}

// =====================================================================
// Batched conversion of all 20 float tensors into bf16 staging in ws.
// =====================================================================
struct ConvSrc { const void* p[20]; };

__global__ __launch_bounds__(256)
void convert_all(ConvSrc s, bf16* __restrict__ ws, const u16* __restrict__ xprobe)
{
  const int n[20] = {8388608, 8388608,
                     262144, 262144, 262144, 262144, 262144, 262144, 262144, 262144,
                     1048576, 2048, 1048576, 512, 512, 512, 512, 512, 512, 512};
  const unsigned int doff[20] = {
      41943040u, 50331648u,
      58720256u, 58982400u, 59244544u, 59506688u,
      59768832u, 60030976u, 60293120u, 60555264u,
      60817408u, 61865984u, 61868032u, 62916608u,
      62917120u, 62917632u, 62918144u, 62918656u, 62919168u, 62919680u};

  const int f32 = is_f32(xprobe);

  int bi = blockIdx.x;
  int idx = 0, b0 = 0;
  for (; idx < 20; ++idx) {
    const int nb = (n[idx] + 2047) >> 11;
    if (bi < b0 + nb) break;
    b0 += nb;
  }
  const int i = ((bi - b0) << 11) + threadIdx.x * 8;
  if (i >= n[idx]) return;
  bf16* dst = ws + doff[idx] + i;
  if (f32) {
    const float* sp = (const float*)s.p[idx] + i;
    f32x4 a = *(const f32x4*)sp;
    f32x4 b = *(const f32x4*)(sp + 4);
    bf16x8 o;
#pragma unroll
    for (int e = 0; e < 4; ++e) { o[e] = (bf16)a[e]; o[4 + e] = (bf16)b[e]; }
    *(bf16x8*)dst = o;
  } else {
    *(bf16x8*)dst = *(const bf16x8*)((const bf16*)s.p[idx] + i);
  }
}

// =====================================================================
// gemm4p body (round-2 verified schedule, BM=256/128), device function
// so one kernel can run two independent GEMM jobs (tail-filling merge).
// Counted vmcnt (6 for BM=256, 4 for BM=128), never 0 in loop.
// XCD remap per job: requires nblk % 8 == 0 (all grids qualify).
// =====================================================================
template<int MODE, int BM>
__device__ __forceinline__ void gemm4p_body(
    const bf16* __restrict__ A, const bf16* __restrict__ B,
    const bf16* __restrict__ bias, bf16* __restrict__ C,
    int N, int K, int gx, int bid, int nblk, bf16* AsP, bf16* BsP)
{
  constexpr int BN = 256, T = 512, WM = 2, WN = 4;
  constexpr int WR = BM / WM;          // rows per wave (128 or 64)
  constexpr int MI = WR / 16;          // M-frags per wave (8 or 4)
  constexpr int NJ = 4;                // 64 cols per wave
  constexpr int MH = MI / 2;           // frags per mh phase (4 or 2)
  constexpr int LA = BM * 8 / T;       // A loads/thread per tile (4 or 2)
  constexpr int LB = 4;
  static_assert(LA == 4 || LA == 2, "schedule assumes BM in {256,128}");

  const int t    = threadIdx.x;
  const int lane = t & 63;
  const int quad = lane >> 4;
  const int l15  = lane & 15;
  const int wave = t >> 6;
  const int wm   = wave >> 2;
  const int wn   = wave & 3;

  const int chunk = nblk >> 3;
  const int lin   = (bid & 7) * chunk + (bid >> 3);
  const int m0    = (lin / gx) * BM;
  const int n0    = (lin % gx) * BN;

  const bf16* Ag = A + (size_t)m0 * K;
  const bf16* Bg = B + (size_t)n0 * K;
  const int wbase = wave << 6;

  auto stA = [&](int kt, int r, int buf) {
    const int s   = r * T + t;
    const int row = s >> 3;
    const int cg  = s & 7;
    async_copy16(Ag + (size_t)row * K + (kt << 6) + ((cg ^ (row & 7)) << 3),
                 AsP + buf * (BM * 64) + ((size_t)(r * T + wbase) << 3));
  };
  auto stB = [&](int kt, int r, int buf) {
    const int s   = r * T + t;
    const int row = s >> 3;
    const int cg  = s & 7;
    async_copy16(Bg + (size_t)row * K + (kt << 6) + ((cg ^ (row & 7)) << 3),
                 BsP + buf * (BN * 64) + ((size_t)(r * T + wbase) << 3));
  };
  auto ldfrag = [&](const bf16* base, int row, int ks) -> bf16x8 {
    return *(const bf16x8*)(base + row * 64 + ((((ks << 2) + quad) ^ (row & 7)) << 3));
  };

  const f32x4 fz = {0.f, 0.f, 0.f, 0.f};
  f32x4 acc[MI][NJ];
#pragma unroll
  for (int i = 0; i < MI; ++i)
#pragma unroll
    for (int j = 0; j < NJ; ++j) acc[i][j] = fz;

  const int nkt = K >> 6;

  // ---- prologue ----
#pragma unroll
  for (int r = 0; r < LA; ++r) stA(0, r, 0);
#pragma unroll
  for (int r = 0; r < LB; ++r) stB(0, r, 0);
  if constexpr (LA == 4) { stA(1, 0, 1); stA(1, 2, 1); }
#pragma unroll
  for (int r = 0; r < LB; ++r) stB(1, r, 1);
  if constexpr (LA == 4) asm volatile("s_waitcnt vmcnt(6)" ::: "memory");
  else                   asm volatile("s_waitcnt vmcnt(4)" ::: "memory");
  __builtin_amdgcn_s_barrier();

  for (int j = 0; j < nkt; ++j) {
    const int cb = j & 1;
    const bf16* a_l = AsP + cb * (BM * 64);
    const bf16* b_l = BsP + cb * (BN * 64);
    const int kN = (j + 1 < nkt) ? j + 1 : nkt - 1;
    const int kF = (j + 2 < nkt) ? j + 2 : nkt - 1;

    bf16x8 bfv[NJ];
    bf16x8 af[MH];

    // ---------------- p0: (mh0, ks0) ----------------
#pragma unroll
    for (int nj = 0; nj < NJ; ++nj) bfv[nj] = ldfrag(b_l, wn * 64 + nj * 16 + l15, 0);
#pragma unroll
    for (int mi = 0; mi < MH; ++mi) af[mi] = ldfrag(a_l, wm * WR + mi * 16 + l15, 0);
    if constexpr (LA == 4) { stA(kN, 1, cb ^ 1); stA(kN, 3, cb ^ 1); }
    else                   { stA(kN, 0, cb ^ 1); stA(kN, 1, cb ^ 1); }
    __builtin_amdgcn_s_barrier();
    asm volatile("s_waitcnt lgkmcnt(0)" ::: "memory");
    __builtin_amdgcn_sched_barrier(0);
    __builtin_amdgcn_s_setprio(1);
#pragma unroll
    for (int mi = 0; mi < MH; ++mi)
#pragma unroll
      for (int nj = 0; nj < NJ; ++nj)
        acc[mi][nj] = __builtin_amdgcn_mfma_f32_16x16x32_bf16(af[mi], bfv[nj],
                                                              acc[mi][nj], 0, 0, 0);
    __builtin_amdgcn_s_setprio(0);
    __builtin_amdgcn_s_barrier();

    // ---------------- p1: (mh1, ks0) ----------------
#pragma unroll
    for (int mi = 0; mi < MH; ++mi) af[mi] = ldfrag(a_l, wm * WR + (MH + mi) * 16 + l15, 0);
    __builtin_amdgcn_s_barrier();
    asm volatile("s_waitcnt lgkmcnt(0)" ::: "memory");
    __builtin_amdgcn_sched_barrier(0);
    __builtin_amdgcn_s_setprio(1);
#pragma unroll
    for (int mi = 0; mi < MH; ++mi)
#pragma unroll
      for (int nj = 0; nj < NJ; ++nj)
        acc[MH + mi][nj] = __builtin_amdgcn_mfma_f32_16x16x32_bf16(af[mi], bfv[nj],
                                                                   acc[MH + mi][nj], 0, 0, 0);
    __builtin_amdgcn_s_setprio(0);
    __builtin_amdgcn_s_barrier();

    // ---------------- p2: (mh0, ks1) ----------------
#pragma unroll
    for (int nj = 0; nj < NJ; ++nj) bfv[nj] = ldfrag(b_l, wn * 64 + nj * 16 + l15, 1);
#pragma unroll
    for (int mi = 0; mi < MH; ++mi) af[mi] = ldfrag(a_l, wm * WR + mi * 16 + l15, 1);
    __builtin_amdgcn_s_barrier();
    asm volatile("s_waitcnt lgkmcnt(0)" ::: "memory");
    __builtin_amdgcn_sched_barrier(0);
    __builtin_amdgcn_s_setprio(1);
#pragma unroll
    for (int mi = 0; mi < MH; ++mi)
#pragma unroll
      for (int nj = 0; nj < NJ; ++nj)
        acc[mi][nj] = __builtin_amdgcn_mfma_f32_16x16x32_bf16(af[mi], bfv[nj],
                                                              acc[mi][nj], 0, 0, 0);
    __builtin_amdgcn_s_setprio(0);
    __builtin_amdgcn_s_barrier();

    // ---------------- p3: (mh1, ks1) ----------------
#pragma unroll
    for (int mi = 0; mi < MH; ++mi) af[mi] = ldfrag(a_l, wm * WR + (MH + mi) * 16 + l15, 1);
    if constexpr (LA == 4) { stA(kF, 0, cb); stA(kF, 2, cb); }
#pragma unroll
    for (int r = 0; r < LB; ++r) stB(kF, r, cb);
    __builtin_amdgcn_s_barrier();
    asm volatile("s_waitcnt lgkmcnt(0)" ::: "memory");
    __builtin_amdgcn_sched_barrier(0);
    __builtin_amdgcn_s_setprio(1);
#pragma unroll
    for (int mi = 0; mi < MH; ++mi)
#pragma unroll
      for (int nj = 0; nj < NJ; ++nj)
        acc[MH + mi][nj] = __builtin_amdgcn_mfma_f32_16x16x32_bf16(af[mi], bfv[nj],
                                                                   acc[MH + mi][nj], 0, 0, 0);
    __builtin_amdgcn_s_setprio(0);
    if constexpr (LA == 4) asm volatile("s_waitcnt vmcnt(6)" ::: "memory");
    else                   asm volatile("s_waitcnt vmcnt(4)" ::: "memory");
    __builtin_amdgcn_s_barrier();
  }

  asm volatile("s_waitcnt vmcnt(0)" ::: "memory");    // drain LDS-DMA

  // ---- epilogue ----
#pragma unroll
  for (int mi = 0; mi < MI; ++mi) {
    const int m = m0 + wm * WR + mi * 16 + quad * 4;
#pragma unroll
    for (int nj = 0; nj < NJ; ++nj) {
      const int n = n0 + wn * 64 + nj * 16 + l15;
      float bv = 0.f;
      if (MODE >= 1) bv = (float)bias[n];
#pragma unroll
      for (int r = 0; r < 4; ++r) {
        float v = acc[mi][nj][r];
        if (MODE >= 1) v += bv;
        if (MODE == 1) v = v > 0.f ? v : 0.01f * v;
        C[(size_t)(m + r) * N + n] = (bf16)v;
      }
    }
  }
}

template<int MODE, int BM>
__global__ __launch_bounds__(512, 1)
void gemm4p(const bf16* __restrict__ A, const bf16* __restrict__ B,
            const bf16* __restrict__ bias, bf16* __restrict__ C,
            int N, int K, int gx)
{
  __shared__ __attribute__((aligned(16))) bf16 As[2 * BM * 64];
  __shared__ __attribute__((aligned(16))) bf16 Bs[2 * 256 * 64];
  gemm4p_body<MODE, BM>(A, B, bias, C, N, K, gx, blockIdx.x, gridDim.x, As, Bs);
}

// Merged QKV (384 blocks) + KV2 (256 blocks); outputs must be disjoint
// (QKV spans 3*MD from C0, KV2 spans 2*MD from C1).
__global__ __launch_bounds__(512, 1)
void gemm4p_dual(const bf16* __restrict__ A0, const bf16* __restrict__ B0,
                 bf16* __restrict__ C0,
                 const bf16* __restrict__ A1, const bf16* __restrict__ B1,
                 bf16* __restrict__ C1)
{
  __shared__ __attribute__((aligned(16))) bf16 As[2 * 256 * 64];
  __shared__ __attribute__((aligned(16))) bf16 Bs[2 * 256 * 64];
  const int bid = blockIdx.x;
  if (bid < 384)
    gemm4p_body<0, 256>(A0, B0, nullptr, C0, 1536, 512, 6, bid, 384, As, Bs);
  else
    gemm4p_body<0, 256>(A1, B1, nullptr, C1, 1024, 512, 4, bid - 384, 256, As, Bs);
}

// =====================================================================
// Flash attention v5: round-6 body (static softmax, [72] LDS — proven
// 465us config) with ONE change: coalesced O writeback. Round-8 PMC
// showed attn is memory-bound with 4x write amplification (WRITE_SIZE
// 66MB vs 16MB useful O) from scalar 2B global stores hitting partial
// 64B lines (RMW also inflated FETCH to 105MB). Fix: stage the wave's
// 32x64 O tile in the (dead after PV) Ps[wave] region via the proven
// stride-72 scalar LDS writes, then 4 passes of b128 global stores —
// 8 lanes cover one row's full 128B segment (h*64 base is 128B-aligned)
// -> every store is 2 full cache lines.
// =====================================================================
__global__ __launch_bounds__(256, 4)
void flash_attn(const bf16* __restrict__ Qp, const bf16* __restrict__ Kp,
                const bf16* __restrict__ Vp, bf16* __restrict__ Op,
                const int* __restrict__ vlen, int per_query, int sq, int skv)
{
  __shared__ __attribute__((aligned(16))) bf16 Ks[64][72];
  __shared__ __attribute__((aligned(16))) bf16 VsT[64][72];   // [d][k]
  __shared__ __attribute__((aligned(16))) bf16 Ps[4][32][72]; // per-wave [q][k]
  __shared__ int vlmax_sh;

  const int t    = threadIdx.x;
  const int wave = t >> 6;
  const int lane = t & 63;
  const int quad = lane >> 4;
  const int l15  = lane & 15;
  const int bx   = blockIdx.x;
  const int qt   = bx >> 8;          // 0..3 (slowest)
  const int h    = bx & 7;
  const int b    = (bx >> 3) & 31;
  const int q0   = qt * 128 + wave * 32;

  bf16x8 qfrag[2][2];
#pragma unroll
  for (int mt = 0; mt < 2; ++mt)
#pragma unroll
    for (int ks = 0; ks < 2; ++ks)
      qfrag[mt][ks] = *(const bf16x8*)(Qp +
          (size_t)(b * 512 + q0 + mt * 16 + l15) * sq + h * 64 + ks * 32 + quad * 8);

  int vl_r[2][4];
  int myvl = 1;
#pragma unroll
  for (int mt = 0; mt < 2; ++mt)
#pragma unroll
    for (int r = 0; r < 4; ++r) {
      const int q = q0 + mt * 16 + quad * 4 + r;
      const int v = per_query ? vlen[b * 512 + q] : vlen[b];
      vl_r[mt][r] = v;
      myvl = v > myvl ? v : myvl;
    }

  if (t == 0) vlmax_sh = 1;
  __syncthreads();
#pragma unroll
  for (int off = 1; off < 64; off <<= 1) {
    const int o = __shfl_xor(myvl, off);
    myvl = o > myvl ? o : myvl;
  }
  if (lane == 0) atomicMax(&vlmax_sh, myvl);
  __syncthreads();
  const int ktiles = (vlmax_sh + 63) >> 6;

  const f32x4 fz = {0.f, 0.f, 0.f, 0.f};
  float l_part[2][4] = {{0.f,0.f,0.f,0.f},{0.f,0.f,0.f,0.f}};
  f32x4 o_acc[2][4];
#pragma unroll
  for (int mt = 0; mt < 2; ++mt)
#pragma unroll
    for (int nt = 0; nt < 4; ++nt) o_acc[mt][nt] = fz;

  for (int kt = 0; kt < ktiles; ++kt) {
    const int k0 = kt * 64;
    __syncthreads();   // prior K/V tiles fully consumed
    {
      const int r0 = t >> 3;
      const int c0 = (t & 7) * 8;
      const bf16* g = Kp + (size_t)(b * 512 + k0 + r0) * skv + h * 64 + c0;
      *(bf16x8*)&Ks[r0][c0]      = *(const bf16x8*)g;
      *(bf16x8*)&Ks[r0 + 32][c0] = *(const bf16x8*)(g + (size_t)32 * skv);
    }
    {
      const bf16* g = Vp + (size_t)(b * 512 + k0 + wave * 16) * skv + h * 64 + lane;
      bf16x8 lo, hi;
#pragma unroll
      for (int kk = 0; kk < 8; ++kk) lo[kk] = g[(size_t)kk * skv];
#pragma unroll
      for (int kk = 0; kk < 8; ++kk) hi[kk] = g[(size_t)(kk + 8) * skv];
      *(bf16x8*)&VsT[lane][wave * 16]     = lo;
      *(bf16x8*)&VsT[lane][wave * 16 + 8] = hi;
    }
    __syncthreads();

    // ---- QK^T ----
    f32x4 s[2][4];
#pragma unroll
    for (int mt = 0; mt < 2; ++mt)
#pragma unroll
      for (int nt = 0; nt < 4; ++nt) s[mt][nt] = fz;
#pragma unroll
    for (int ks = 0; ks < 2; ++ks)
#pragma unroll
      for (int nt = 0; nt < 4; ++nt) {
        const bf16x8 bk = *(const bf16x8*)&Ks[nt * 16 + l15][ks * 32 + quad * 8];
        s[0][nt] = __builtin_amdgcn_mfma_f32_16x16x32_bf16(qfrag[0][ks], bk, s[0][nt], 0, 0, 0);
        s[1][nt] = __builtin_amdgcn_mfma_f32_16x16x32_bf16(qfrag[1][ks], bk, s[1][nt], 0, 0, 0);
      }

    // ---- static softmax: p = masked ? 0 : exp(s/8); accumulate l ----
#pragma unroll
    for (int mt = 0; mt < 2; ++mt)
#pragma unroll
      for (int nt = 0; nt < 4; ++nt) {
        const int k_abs = k0 + nt * 16 + l15;
#pragma unroll
        for (int r = 0; r < 4; ++r) {
          const float p = (k_abs < vl_r[mt][r]) ? __expf(s[mt][nt][r] * 0.125f) : 0.f;
          l_part[mt][r] += p;
          Ps[wave][mt * 16 + quad * 4 + r][nt * 16 + l15] = (bf16)p;
        }
      }

    // ---- O += P @ V (Ps per-wave; same-wave DS ordering suffices) ----
#pragma unroll
    for (int ks = 0; ks < 2; ++ks) {
      const bf16x8 ap0 = *(const bf16x8*)&Ps[wave][l15][ks * 32 + quad * 8];
      const bf16x8 ap1 = *(const bf16x8*)&Ps[wave][16 + l15][ks * 32 + quad * 8];
#pragma unroll
      for (int nt = 0; nt < 4; ++nt) {
        const bf16x8 bv = *(const bf16x8*)&VsT[nt * 16 + l15][ks * 32 + quad * 8];
        o_acc[0][nt] = __builtin_amdgcn_mfma_f32_16x16x32_bf16(ap0, bv, o_acc[0][nt], 0, 0, 0);
        o_acc[1][nt] = __builtin_amdgcn_mfma_f32_16x16x32_bf16(ap1, bv, o_acc[1][nt], 0, 0, 0);
      }
    }
  }

  // ---- epilogue: scale, stage O tile in Ps[wave] (dead), coalesced store ----
#pragma unroll
  for (int mt = 0; mt < 2; ++mt)
#pragma unroll
    for (int r = 0; r < 4; ++r) {
      float l = l_part[mt][r];
#pragma unroll
      for (int off = 1; off < 16; off <<= 1)
        l += __shfl_xor(l, off);
      const float inv_l = (l > 0.f) ? (1.f / l) : 0.f;
      const int ql = mt * 16 + quad * 4 + r;
#pragma unroll
      for (int nt = 0; nt < 4; ++nt)
        Ps[wave][ql][nt * 16 + l15] = (bf16)(o_acc[mt][nt][r] * inv_l);
    }
  // same-wave DS ordering: the scalar writes above are visible to the
  // vector reads below without a barrier (per-wave Ps region).
#pragma unroll
  for (int pass = 0; pass < 4; ++pass) {
    const int row = pass * 8 + (lane >> 3);   // 0..31 within wave tile
    const int c8  = lane & 7;
    const bf16x8 v = *(const bf16x8*)&Ps[wave][row][c8 * 8];
    *(bf16x8*)(Op + (size_t)(b * 512 + q0 + row) * 512 + h * 64 + c8 * 8) = v;
  }
}

// =====================================================================
// AddNorm (internal, bf16 out). One wave per 512-row.
// =====================================================================
__global__ __launch_bounds__(256)
void add_layernorm(const bf16* X, const bf16* R,
                   const bf16* __restrict__ gamma, const bf16* __restrict__ beta,
                   bf16* Out)
{
  const int t    = threadIdx.x;
  const int wave = t >> 6;
  const int lane = t & 63;
  const size_t row  = (size_t)blockIdx.x * 4 + wave;
  const size_t base = row * 512 + lane * 8;

  bf16x8 xv = *(const bf16x8*)(X + base);
  bf16x8 rv = *(const bf16x8*)(R + base);
  float v[8];
  float sum = 0.f, ss = 0.f;
#pragma unroll
  for (int i = 0; i < 8; ++i) {
    v[i] = (float)xv[i] + (float)rv[i];
    sum += v[i];
    ss  += v[i] * v[i];
  }
#pragma unroll
  for (int off = 1; off < 64; off <<= 1) {
    sum += __shfl_xor(sum, off);
    ss  += __shfl_xor(ss, off);
  }
  const float mean = sum * (1.f / 512.f);
  const float var  = ss * (1.f / 512.f) - mean * mean;
  const float rstd = rsqrtf(var + 1e-5f);

  bf16x8 gv = *(const bf16x8*)(gamma + lane * 8);
  bf16x8 bv = *(const bf16x8*)(beta + lane * 8);
  bf16x8 ov;
#pragma unroll
  for (int i = 0; i < 8; ++i)
    ov[i] = (bf16)(((v[i] - mean) * rstd) * (float)gv[i] + (float)bv[i]);
  *(bf16x8*)(Out + base) = ov;
}

// =====================================================================
// Final AddNorm: writes d_out as fp32 or bf16 per the inline dtype probe.
// =====================================================================
__global__ __launch_bounds__(256)
void add_layernorm_out(const bf16* X, const bf16* R,
                       const bf16* __restrict__ gamma, const bf16* __restrict__ beta,
                       void* Out, const u16* __restrict__ xprobe)
{
  const int t    = threadIdx.x;
  const int wave = t >> 6;
  const int lane = t & 63;
  const size_t row  = (size_t)blockIdx.x * 4 + wave;
  const size_t base = row * 512 + lane * 8;

  const int f32 = is_f32(xprobe);

  bf16x8 xv = *(const bf16x8*)(X + base);
  bf16x8 rv = *(const bf16x8*)(R + base);
  float v[8];
  float sum = 0.f, ss = 0.f;
#pragma unroll
  for (int i = 0; i < 8; ++i) {
    v[i] = (float)xv[i] + (float)rv[i];
    sum += v[i];
    ss  += v[i] * v[i];
  }
#pragma unroll
  for (int off = 1; off < 64; off <<= 1) {
    sum += __shfl_xor(sum, off);
    ss  += __shfl_xor(ss, off);
  }
  const float mean = sum * (1.f / 512.f);
  const float var  = ss * (1.f / 512.f) - mean * mean;
  const float rstd = rsqrtf(var + 1e-5f);

  bf16x8 gv = *(const bf16x8*)(gamma + lane * 8);
  bf16x8 bv = *(const bf16x8*)(beta + lane * 8);
  float o[8];
#pragma unroll
  for (int i = 0; i < 8; ++i)
    o[i] = ((v[i] - mean) * rstd) * (float)gv[i] + (float)bv[i];

  if (f32) {
    float* op = (float*)Out + base;
    f32x4 o0 = {o[0], o[1], o[2], o[3]};
    f32x4 o1 = {o[4], o[5], o[6], o[7]};
    *(f32x4*)op       = o0;
    *(f32x4*)(op + 4) = o1;
  } else {
    bf16x8 ov;
#pragma unroll
    for (int i = 0; i < 8; ++i) ov[i] = (bf16)o[i];
    *(bf16x8*)((bf16*)Out + base) = ov;
  }
}

// =====================================================================
// Lifetime map (round-6 verified):
//   dual : reads Xb(S5),Eb(S6),W   writes QKV->S0..S2, KV2->S3..S4
//   attn1: reads S0-span(QKV)      writes O1 -> Eb      [Eb dead]
//   Wo1  : reads S6(Eb)            writes X2 -> S0      [QKV dead]
//   LN1  : reads Xb,S0             writes Y  -> S1
//   Wq2  : reads S1                writes Q2 -> S2
//   attn2: reads S2, S3..S4(KV2)   writes O2 -> S0
//   Wo2  : reads S0                writes Y2 -> S2
//   LN2  : reads S1,S2             writes Z  -> S4      [KV2 dead]
//   FFN1 : reads S4                writes H  -> S0..S3
//   FFN2 : reads S0..S3            writes F  -> Xb      [Xb dead]
//   LN3  : reads S4,Xb             writes d_out
// =====================================================================
extern "C" void kernel_launch(void* const* d_in, const int* in_sizes, int n_in,
                              void* d_out, int out_size, void* d_ws, size_t ws_size,
                              hipStream_t stream)
{
  (void)in_sizes; (void)n_in; (void)out_size; (void)ws_size;

  const int* dvl = (const int*)d_in[2];
  const int* evl = (const int*)d_in[3];
  const u16* xprobe = (const u16*)d_in[0];

  bf16* ws = (bf16*)d_ws;
  bf16* S0 = ws;
  bf16* S1 = ws + 1 * MD;
  bf16* S2 = ws + 2 * MD;
  bf16* S3 = ws + 3 * MD;
  bf16* S4 = ws + 4 * MD;
  bf16* Xb = ws + 5 * MD;
  bf16* Eb = ws + 6 * MD;
  bf16* W  = ws + 7 * MD;
  const bf16 *Wq1 = W,
             *Wo1 = W + 786432,   *Wq2 = W + 1048576, *Wk2 = W + 1310720,
             *Wo2 = W + 1835008,
             *W1  = W + 2097152,  *b1  = W + 3145728,
             *W2  = W + 3147776,  *b2  = W + 4196352,
             *g1  = W + 4196864,  *be1 = W + 4197376,
             *g2  = W + 4197888,  *be2 = W + 4198400,
             *g3  = W + 4198912,  *be3 = W + 4199424;

  // ---- ingest (dtype probe inlined per wave) ----
  ConvSrc cs;
  cs.p[0] = d_in[0];  cs.p[1] = d_in[1];
  for (int k = 0; k < 12; ++k) cs.p[2 + k] = d_in[4 + k];
  for (int k = 0; k < 6; ++k)  cs.p[14 + k] = d_in[16 + k];
  convert_all<<<dim3(10248), dim3(256), 0, stream>>>(cs, ws, xprobe);

  dim3 blk256(256);
  dim3 blk512(512);

  // ---- QKV + KV2 merged: disjoint outputs S0..S2 / S3..S4 ----
  gemm4p_dual<<<dim3(640), blk512, 0, stream>>>(Xb, Wq1, S0, Eb, Wk2, S3);

  // ---- self-attention ----
  flash_attn<<<dim3(1024), blk256, 0, stream>>>(S0, S0 + 512, S0 + 1024, Eb, dvl, 1, 1536, 1536);
  gemm4p<0,128><<<dim3(256), blk512, 0, stream>>>(Eb, Wo1, nullptr, S0, 512, 512, 2);
  add_layernorm<<<dim3(4096), blk256, 0, stream>>>(Xb, S0, g1, be1, S1);   // Y

  // ---- cross-attention (KV2 in S3..S4) ----
  gemm4p<0,128><<<dim3(256), blk512, 0, stream>>>(S1, Wq2, nullptr, S2, 512, 512, 2);
  flash_attn<<<dim3(1024), blk256, 0, stream>>>(S2, S3, S3 + 512, S0, evl, 0, 512, 1024);
  gemm4p<0,128><<<dim3(256), blk512, 0, stream>>>(S0, Wo2, nullptr, S2, 512, 512, 2);
  add_layernorm<<<dim3(4096), blk256, 0, stream>>>(S1, S2, g2, be2, S4);   // Z

  // ---- FFN ----
  gemm4p<1,256><<<dim3(512), blk512, 0, stream>>>(S4, W1, b1, S0, 2048, 512, 8);
  gemm4p<2,128><<<dim3(256), blk512, 0, stream>>>(S0, W2, b2, Xb, 512, 2048, 2);
  add_layernorm_out<<<dim3(4096), blk256, 0, stream>>>(S4, Xb, g3, be3, d_out, xprobe);
}